// Round 8
// baseline (411.699 us; speedup 1.0000x reference)
//
#include <hip/hip_runtime.h>
#include <hip/hip_fp16.h>

#define N_NODES 100000
#define N_EDGES 1600000
#define N_GRAPHS 512
#define F_IN 20
#define HID 128
#define OUT_F 64

#define BUCKETS 256
#define SPAN 391        // ceil(N_NODES / BUCKETS)
#define BCAP 7000       // per-bucket capacity (mean 6250, ~9 sigma headroom)
#define EPB 2048        // edges per partition block

typedef _Float16 half8_t __attribute__((ext_vector_type(8)));
typedef float f32x4_t __attribute__((ext_vector_type(4)));

__device__ inline float4 h4_to_f4(uint2 u) {
    __half2 h0 = *(__half2*)&u.x;
    __half2 h1 = *(__half2*)&u.y;
    float2 f0 = __half22float2(h0);
    float2 f1 = __half22float2(h1);
    return make_float4(f0.x, f0.y, f1.x, f1.y);
}

// ---------------- partition edges into 256 dst-range buckets ----------------
// Per-wave LDS histograms (collision degree /4); phase-A atomic return value
// is reused as the write rank (1 LDS atomic per edge total).
__global__ __launch_bounds__(256) void partition(const int* __restrict__ src,
                                                 const int* __restrict__ dst,
                                                 int* __restrict__ bpairs,
                                                 int* cur256) {
    __shared__ int lcnt[4][BUCKETS];
    __shared__ int woff[4][BUCKETS];
    int t = threadIdx.x;
    int wv = t >> 6;
    for (int i = t; i < 4 * BUCKETS; i += 256) ((int*)lcnt)[i] = 0;
    __syncthreads();
    int base = blockIdx.x * EPB;
    int myb[8], myp[8], myr[8];
#pragma unroll
    for (int i = 0; i < 8; ++i) {
        int e = base + i * 256 + t;
        int b = -1, p = 0, rk = 0;
        if (e < N_EDGES) {
            int s = src[e], d = dst[e];
            b = d / SPAN;
            p = (s << 9) | (d - b * SPAN);
            rk = atomicAdd(&lcnt[wv][b], 1);
        }
        myb[i] = b; myp[i] = p; myr[i] = rk;
    }
    __syncthreads();
    {
        int c0 = lcnt[0][t], c1 = lcnt[1][t], c2 = lcnt[2][t], c3 = lcnt[3][t];
        int gb = atomicAdd(&cur256[t], c0 + c1 + c2 + c3);
        woff[0][t] = gb;
        woff[1][t] = gb + c0;
        woff[2][t] = gb + c0 + c1;
        woff[3][t] = gb + c0 + c1 + c2;
    }
    __syncthreads();
#pragma unroll
    for (int i = 0; i < 8; ++i) {
        int b = myb[i];
        if (b >= 0) {
            int p = woff[wv][b] + myr[i];
            if (p < BCAP) bpairs[(size_t)b * BCAP + p] = myp[i];
        }
    }
}

// ---------------- exclusive scan of bucket counts ----------------
__global__ void scan_bbase(const int* __restrict__ cur256, int* bbase, int* row_st) {
    __shared__ int sc[BUCKETS];
    int t = threadIdx.x;
    int v = cur256[t];
    sc[t] = v;
    __syncthreads();
    for (int o = 1; o < BUCKETS; o <<= 1) {
        int x = (t >= o) ? sc[t - o] : 0;
        __syncthreads();
        sc[t] += x;
        __syncthreads();
    }
    bbase[t] = sc[t] - v;
    if (t == 0) row_st[N_NODES] = N_EDGES;
}

// ---------------- per-bucket CSR build ----------------
__global__ __launch_bounds__(256) void csr_build(const int* __restrict__ bpairs,
                                                 const int* __restrict__ bcnt,
                                                 const int* __restrict__ bbase,
                                                 int* __restrict__ row_st,
                                                 int* __restrict__ csr) {
    __shared__ int ocnt[SPAN];
    __shared__ int sc[512];
    __shared__ int cur[SPAN];
    int b = blockIdx.x, t = threadIdx.x;
    int n0 = b * SPAN;
    int span = N_NODES - n0; if (span > SPAN) span = SPAN;
    for (int i = t; i < SPAN; i += 256) ocnt[i] = 0;
    __syncthreads();
    int n = bcnt[b];
    const int* p = bpairs + (size_t)b * BCAP;
    for (int i = t; i < n; i += 256) atomicAdd(&ocnt[p[i] & 511], 1);
    __syncthreads();
    sc[t]       = (t < span) ? ocnt[t] : 0;
    sc[t + 256] = (t + 256 < span) ? ocnt[t + 256] : 0;
    __syncthreads();
    for (int o = 1; o < 512; o <<= 1) {
        int a0 = (t >= o) ? sc[t - o] : 0;
        int a1 = sc[t + 256 - o];
        __syncthreads();
        sc[t] += a0;
        sc[t + 256] += a1;
        __syncthreads();
    }
    int base = bbase[b];
    for (int i = t; i < span; i += 256) {
        int start = sc[i] - ocnt[i];
        row_st[n0 + i] = base + start;
        cur[i] = start;
    }
    __syncthreads();
    for (int i = t; i < n; i += 256) {
        int e = p[i];
        int lp = atomicAdd(&cur[e & 511], 1);
        csr[base + lp] = e >> 9;
    }
}

// ---------------- layer 1: Xs = fp16(dinv * x), rows padded to 32 halves ----------------
__global__ void scale_x(const float* __restrict__ x, const int* __restrict__ row_st,
                        __half* __restrict__ Xs) {
    int i = blockIdx.x * 256 + threadIdx.x;   // over N_NODES*32
    int n = i >> 5, f = i & 31;
    if (n >= N_NODES) return;
    float v = (f < F_IN) ? x[n * F_IN + f] : 0.f;
    float di = rsqrtf((float)(row_st[n + 1] - row_st[n] + 1));
    Xs[i] = __float2half(di * v);
}

// ---------------- layer 1 fused: gather(F_IN) + GEMM -> H fp16 ----------------
__global__ __launch_bounds__(256) void layer1(const __half* __restrict__ Xs,
                                              const int* __restrict__ row_st,
                                              const int* __restrict__ csr,
                                              const float* __restrict__ W,
                                              const float* __restrict__ bias,
                                              __half* __restrict__ H) {
    __shared__ float Wlds[F_IN * HID];   // 10 KB
    __shared__ float Alds[16 * F_IN];
    const int t = threadIdx.x;
    const int node0 = blockIdx.x * 16;

    for (int i = t; i < F_IN * HID; i += 256) Wlds[i] = W[i];

    // gather phase: half-wave hw handles nodes node0+hw*2, +1
    const int hw = t >> 5, l = t & 31;
    for (int k = 0; k < 2; ++k) {
        int nn = node0 + hw * 2 + k;
        int r0 = row_st[nn], r1 = row_st[nn + 1];
        float acc = __half2float(Xs[nn * 32 + l]);
        int r = r0;
        for (; r + 3 < r1; r += 4) {
            int s0 = csr[r], s1 = csr[r + 1], s2 = csr[r + 2], s3 = csr[r + 3];
            float v0 = __half2float(Xs[s0 * 32 + l]);
            float v1 = __half2float(Xs[s1 * 32 + l]);
            float v2 = __half2float(Xs[s2 * 32 + l]);
            float v3 = __half2float(Xs[s3 * 32 + l]);
            acc += (v0 + v1) + (v2 + v3);
        }
        for (; r < r1; ++r) acc += __half2float(Xs[csr[r] * 32 + l]);
        float di = rsqrtf((float)(r1 - r0 + 1));
        if (l < F_IN) Alds[(hw * 2 + k) * F_IN + l] = di * acc;
    }
    __syncthreads();

    // GEMM phase
    const int h4 = (t & 31) * 4;
    const int g  = t >> 5;
    float4 b4 = *(const float4*)&bias[h4];
    float4 acc0 = b4;
    float4 acc1 = b4;
#pragma unroll
    for (int kk = 0; kk < F_IN; ++kk) {
        float a0 = Alds[(g * 2) * F_IN + kk];
        float a1 = Alds[(g * 2 + 1) * F_IN + kk];
        float4 w = *(const float4*)&Wlds[kk * HID + h4];
        acc0.x = fmaf(a0, w.x, acc0.x);
        acc0.y = fmaf(a0, w.y, acc0.y);
        acc0.z = fmaf(a0, w.z, acc0.z);
        acc0.w = fmaf(a0, w.w, acc0.w);
        acc1.x = fmaf(a1, w.x, acc1.x);
        acc1.y = fmaf(a1, w.y, acc1.y);
        acc1.z = fmaf(a1, w.z, acc1.z);
        acc1.w = fmaf(a1, w.w, acc1.w);
    }
    {
        __half2 h0 = __floats2half2_rn(acc0.x, acc0.y);
        __half2 h1 = __floats2half2_rn(acc0.z, acc0.w);
        uint2 u; u.x = *(unsigned*)&h0; u.y = *(unsigned*)&h1;
        ((uint2*)H)[(node0 + g * 2) * 32 + (h4 >> 2)] = u;
    }
    {
        __half2 h0 = __floats2half2_rn(acc1.x, acc1.y);
        __half2 h1 = __floats2half2_rn(acc1.z, acc1.w);
        uint2 u; u.x = *(unsigned*)&h0; u.y = *(unsigned*)&h1;
        ((uint2*)H)[(node0 + g * 2 + 1) * 32 + (h4 >> 2)] = u;
    }
}

// ---------------- layers-2/3 GEMM via MFMA: T = dinv * (relu(H) @ W) ----------------
__global__ __launch_bounds__(256) void gemm_mfma(const __half* __restrict__ H,
                                                 const float* __restrict__ W,
                                                 const int* __restrict__ row_st,
                                                 __half* __restrict__ T) {
    __shared__ _Float16 Whi[128 * 128];
    __shared__ _Float16 Wlo[128 * 128];
    const int t = threadIdx.x;

    for (int i = t; i < 128 * 128; i += 256) {
        int k = i >> 7, c = i & 127;
        float w = W[i];
        _Float16 hi = (_Float16)w;
        _Float16 lo = (_Float16)((w - (float)hi) * 2048.0f);
        int addr = c * 128 + (((k >> 3) ^ (c & 15)) << 3) + (k & 7);
        Whi[addr] = hi;
        Wlo[addr] = lo;
    }
    __syncthreads();

    const int wv = t >> 6;
    const int l  = t & 63;
    const int lr = l & 15;
    const int lq = l >> 4;

    for (int rep = 0; rep < 4; ++rep) {
        int strip = (blockIdx.x * 4 + wv) * 4 + rep;
        if (strip >= N_NODES / 16) continue;
        int n0 = strip * 16;

        f32x4_t acc[8], acl[8];
#pragma unroll
        for (int ct = 0; ct < 8; ++ct) { acc[ct] = (f32x4_t){0,0,0,0}; acl[ct] = (f32x4_t){0,0,0,0}; }

#pragma unroll
        for (int kc = 0; kc < 4; ++kc) {
            half8_t a = *(const half8_t*)(H + (size_t)(n0 + lr) * 128 + kc * 32 + lq * 8);
#pragma unroll
            for (int j = 0; j < 8; ++j) a[j] = a[j] > (_Float16)0 ? a[j] : (_Float16)0;
            int g = kc * 4 + lq;
#pragma unroll
            for (int ct = 0; ct < 8; ++ct) {
                int c = ct * 16 + lr;
                int addr = c * 128 + ((g ^ lr) << 3);
                half8_t bh = *(const half8_t*)&Whi[addr];
                half8_t bl = *(const half8_t*)&Wlo[addr];
                acc[ct] = __builtin_amdgcn_mfma_f32_16x16x32_f16(a, bh, acc[ct], 0, 0, 0);
                acl[ct] = __builtin_amdgcn_mfma_f32_16x16x32_f16(a, bl, acl[ct], 0, 0, 0);
            }
        }

        int r0 = n0 + lq * 4;
#pragma unroll
        for (int r = 0; r < 4; ++r) {
            int row = r0 + r;
            float d = rsqrtf((float)(row_st[row + 1] - row_st[row] + 1));
#pragma unroll
            for (int ct = 0; ct < 8; ++ct) {
                float v = (acc[ct][r] + acl[ct][r] * 4.8828125e-4f) * d;
                T[(size_t)row * 128 + ct * 16 + lr] = __float2half(v);
            }
        }
    }
}

// ---------------- gather (fp16 rows, unroll 8) ----------------
__global__ __launch_bounds__(256) void gather_range(const __half* __restrict__ A,
                                                    const int* __restrict__ row_st,
                                                    const int* __restrict__ csr,
                                                    const float* __restrict__ bias,
                                                    __half* __restrict__ B) {
    int t = threadIdx.x;
    int n = blockIdx.x * 8 + (t >> 5);
    int l = t & 31;
    int r0 = row_st[n], r1 = row_st[n + 1];
    float di = rsqrtf((float)(r1 - r0 + 1));
    const uint2* Af = (const uint2*)A;
    float4 acc = h4_to_f4(Af[n * 32 + l]);   // self term
    int r = r0;
    for (; r + 7 < r1; r += 8) {
        int s0 = csr[r],     s1 = csr[r + 1], s2 = csr[r + 2], s3 = csr[r + 3];
        int s4 = csr[r + 4], s5 = csr[r + 5], s6 = csr[r + 6], s7 = csr[r + 7];
        float4 v0 = h4_to_f4(Af[s0 * 32 + l]);
        float4 v1 = h4_to_f4(Af[s1 * 32 + l]);
        float4 v2 = h4_to_f4(Af[s2 * 32 + l]);
        float4 v3 = h4_to_f4(Af[s3 * 32 + l]);
        float4 v4 = h4_to_f4(Af[s4 * 32 + l]);
        float4 v5 = h4_to_f4(Af[s5 * 32 + l]);
        float4 v6 = h4_to_f4(Af[s6 * 32 + l]);
        float4 v7 = h4_to_f4(Af[s7 * 32 + l]);
        acc.x += ((v0.x + v1.x) + (v2.x + v3.x)) + ((v4.x + v5.x) + (v6.x + v7.x));
        acc.y += ((v0.y + v1.y) + (v2.y + v3.y)) + ((v4.y + v5.y) + (v6.y + v7.y));
        acc.z += ((v0.z + v1.z) + (v2.z + v3.z)) + ((v4.z + v5.z) + (v6.z + v7.z));
        acc.w += ((v0.w + v1.w) + (v2.w + v3.w)) + ((v4.w + v5.w) + (v6.w + v7.w));
    }
    for (; r + 3 < r1; r += 4) {
        int s0 = csr[r], s1 = csr[r + 1], s2 = csr[r + 2], s3 = csr[r + 3];
        float4 v0 = h4_to_f4(Af[s0 * 32 + l]);
        float4 v1 = h4_to_f4(Af[s1 * 32 + l]);
        float4 v2 = h4_to_f4(Af[s2 * 32 + l]);
        float4 v3 = h4_to_f4(Af[s3 * 32 + l]);
        acc.x += (v0.x + v1.x) + (v2.x + v3.x);
        acc.y += (v0.y + v1.y) + (v2.y + v3.y);
        acc.z += (v0.z + v1.z) + (v2.z + v3.z);
        acc.w += (v0.w + v1.w) + (v2.w + v3.w);
    }
    for (; r < r1; ++r) {
        float4 v = h4_to_f4(Af[csr[r] * 32 + l]);
        acc.x += v.x; acc.y += v.y; acc.z += v.z; acc.w += v.w;
    }
    float4 b4 = ((const float4*)bias)[l];
    __half2 h0 = __floats2half2_rn(fmaf(di, acc.x, b4.x), fmaf(di, acc.y, b4.y));
    __half2 h1 = __floats2half2_rn(fmaf(di, acc.z, b4.z), fmaf(di, acc.w, b4.w));
    uint2 u; u.x = *(unsigned*)&h0; u.y = *(unsigned*)&h1;
    ((uint2*)B)[n * 32 + l] = u;
}

// ---------------- pooling (fp16 input, fused counting; batch sorted) ----------------
__global__ __launch_bounds__(256) void pool(const __half* __restrict__ B,
                                            const int* __restrict__ batch,
                                            float* sums, float* counts) {
    int t = threadIdx.x;
    int grp = blockIdx.x * 8 + (t >> 5);
    int l = t & 31;
    int h4 = l * 4;
    int n0 = grp * 8;
    if (n0 >= N_NODES) return;
    const uint2* Bf = (const uint2*)B;
    int cur = batch[n0];
    int runlen = 0;
    float4 acc = make_float4(0.f, 0.f, 0.f, 0.f);
    for (int k = 0; k < 8; ++k) {
        int n = n0 + k;
        if (n >= N_NODES) break;
        int g = batch[n];
        if (g != cur) {
            float* sp = &sums[cur * HID + h4];
            atomicAdd(sp + 0, acc.x); atomicAdd(sp + 1, acc.y);
            atomicAdd(sp + 2, acc.z); atomicAdd(sp + 3, acc.w);
            if (l == 0) atomicAdd(&counts[cur], (float)runlen);
            acc = make_float4(0.f, 0.f, 0.f, 0.f);
            runlen = 0;
            cur = g;
        }
        float4 v = h4_to_f4(Bf[n * 32 + l]);
        acc.x += fmaxf(v.x, 0.f);
        acc.y += fmaxf(v.y, 0.f);
        acc.z += fmaxf(v.z, 0.f);
        acc.w += fmaxf(v.w, 0.f);
        ++runlen;
    }
    float* sp = &sums[cur * HID + h4];
    atomicAdd(sp + 0, acc.x); atomicAdd(sp + 1, acc.y);
    atomicAdd(sp + 2, acc.z); atomicAdd(sp + 3, acc.w);
    if (l == 0) atomicAdd(&counts[cur], (float)runlen);
}

__global__ void final_gemm(const float* __restrict__ sums, const float* __restrict__ counts,
                           const float* __restrict__ Wout, const float* __restrict__ bout,
                           float* __restrict__ out) {
    int g = blockIdx.x;
    int o = threadIdx.x;   // 64
    __shared__ float p[HID];
    for (int k = o; k < HID; k += 64) p[k] = sums[g * HID + k];
    __syncthreads();
    float inv = 1.0f / fmaxf(counts[g], 1.0f);
    float acc = 0.f;
#pragma unroll 8
    for (int k = 0; k < HID; ++k)
        acc = fmaf(p[k], Wout[k * OUT_F + o], acc);
    out[g * OUT_F + o] = fmaf(inv, acc, bout[o]);
}

extern "C" void kernel_launch(void* const* d_in, const int* in_sizes, int n_in,
                              void* d_out, int out_size, void* d_ws, size_t ws_size,
                              hipStream_t stream) {
    const float* x     = (const float*)d_in[0];
    const int*   ei    = (const int*)d_in[1];
    const int*   batch = (const int*)d_in[2];
    const float* W1    = (const float*)d_in[3];
    const float* b1    = (const float*)d_in[4];
    const float* W2    = (const float*)d_in[5];
    const float* b2    = (const float*)d_in[6];
    const float* W3    = (const float*)d_in[7];
    const float* b3    = (const float*)d_in[8];
    const float* Wout  = (const float*)d_in[9];
    const float* bout  = (const float*)d_in[10];
    float* out = (float*)d_out;

    const int* src = ei;
    const int* dst = ei + N_EDGES;

    // workspace (same proven footprint as rounds 4-7)
    float* A      = (float*)d_ws;                        // 12.8M floats
    float* Breg   = A + (size_t)N_NODES * HID;           // 12.8M floats
    int*   row_st = (int*)(Breg + (size_t)N_NODES * HID);// 100001 ints
    float* sums   = (float*)(row_st + N_NODES + 1);      // 65536
    float* counts = sums + N_GRAPHS * HID;               // 512
    int*   csr    = (int*)(counts + N_GRAPHS);           // 1.6M ints
    int*   cur256 = csr + N_EDGES;                       // 256
    int*   bbase  = cur256 + BUCKETS;                    // 256

    int*    bpairs = (int*)A;             // 7.2 MB overlay, dead after csr_build
    __half* Xs     = (__half*)A;          // N_NODES*32 halves (6.4 MB), after csr_build
    __half* T      = (__half*)A;          // fp16 message table (25.6 MB), after layer1
    __half* H      = (__half*)Breg;       // fp16 activation table (25.6 MB)

    // 1. zero (async memset, capture-safe) + CSR build
    hipMemsetAsync(sums, 0, (N_GRAPHS * HID + N_GRAPHS) * sizeof(float), stream);
    hipMemsetAsync(cur256, 0, BUCKETS * sizeof(int), stream);
    partition<<<(N_EDGES + EPB - 1) / EPB, 256, 0, stream>>>(src, dst, bpairs, cur256);
    scan_bbase<<<1, BUCKETS, 0, stream>>>(cur256, bbase, row_st);
    csr_build<<<BUCKETS, 256, 0, stream>>>(bpairs, cur256, bbase, row_st, csr);

    // 2. layer 1: scale, then fused gather(F_IN)+GEMM
    scale_x<<<N_NODES * 32 / 256, 256, 0, stream>>>(x, row_st, Xs);
    layer1<<<N_NODES / 16, 256, 0, stream>>>(Xs, row_st, csr, W1, b1, H);

    // 3. layers 2/3: MFMA transform (ReLU fused) then aggregate
    gemm_mfma<<<391, 256, 0, stream>>>(H, W2, row_st, T);
    gather_range<<<N_NODES / 8, 256, 0, stream>>>(T, row_st, csr, b2, H);
    gemm_mfma<<<391, 256, 0, stream>>>(H, W3, row_st, T);
    gather_range<<<N_NODES / 8, 256, 0, stream>>>(T, row_st, csr, b3, H);

    // 4. pool + head
    pool<<<(N_NODES / 8 + 7) / 8, 256, 0, stream>>>(H, batch, sums, counts);
    final_gemm<<<N_GRAPHS, 64, 0, stream>>>(sums, counts, Wout, bout, out);
}

// Round 9
// 405.120 us; speedup vs baseline: 1.0162x; 1.0162x over previous
//
#include <hip/hip_runtime.h>
#include <hip/hip_fp16.h>

#define N_NODES 100000
#define N_EDGES 1600000
#define N_GRAPHS 512
#define F_IN 20
#define HID 128
#define OUT_F 64

#define BUCKETS 256
#define SPAN 391        // ceil(N_NODES / BUCKETS)
#define BCAP 7000       // per-bucket capacity (mean 6250, ~9 sigma headroom)
#define EPB 2048        // edges per partition block

typedef _Float16 half8_t __attribute__((ext_vector_type(8)));
typedef float f32x4_t __attribute__((ext_vector_type(4)));

__device__ inline float4 h4_to_f4(uint2 u) {
    __half2 h0 = *(__half2*)&u.x;
    __half2 h1 = *(__half2*)&u.y;
    float2 f0 = __half22float2(h0);
    float2 f1 = __half22float2(h1);
    return make_float4(f0.x, f0.y, f1.x, f1.y);
}

// ---------------- partition edges into 256 dst-range buckets ----------------
__global__ __launch_bounds__(256) void partition(const int* __restrict__ src,
                                                 const int* __restrict__ dst,
                                                 int* __restrict__ bpairs,
                                                 int* cur256) {
    __shared__ int lcnt[4][BUCKETS];
    __shared__ int woff[4][BUCKETS];
    int t = threadIdx.x;
    int wv = t >> 6;
    for (int i = t; i < 4 * BUCKETS; i += 256) ((int*)lcnt)[i] = 0;
    __syncthreads();
    int base = blockIdx.x * EPB;
    int myb[8], myp[8], myr[8];
#pragma unroll
    for (int i = 0; i < 8; ++i) {
        int e = base + i * 256 + t;
        int b = -1, p = 0, rk = 0;
        if (e < N_EDGES) {
            int s = src[e], d = dst[e];
            b = d / SPAN;
            p = (s << 9) | (d - b * SPAN);
            rk = atomicAdd(&lcnt[wv][b], 1);
        }
        myb[i] = b; myp[i] = p; myr[i] = rk;
    }
    __syncthreads();
    {
        int c0 = lcnt[0][t], c1 = lcnt[1][t], c2 = lcnt[2][t], c3 = lcnt[3][t];
        int gb = atomicAdd(&cur256[t], c0 + c1 + c2 + c3);
        woff[0][t] = gb;
        woff[1][t] = gb + c0;
        woff[2][t] = gb + c0 + c1;
        woff[3][t] = gb + c0 + c1 + c2;
    }
    __syncthreads();
#pragma unroll
    for (int i = 0; i < 8; ++i) {
        int b = myb[i];
        if (b >= 0) {
            int p = woff[wv][b] + myr[i];
            if (p < BCAP) bpairs[(size_t)b * BCAP + p] = myp[i];
        }
    }
}

// ---------------- per-bucket CSR build (fused bbase scan + scale_x) ----------------
__global__ __launch_bounds__(256) void csr_build(const int* __restrict__ bpairs,
                                                 const int* __restrict__ cur256,
                                                 int* __restrict__ row_st,
                                                 int* __restrict__ csr,
                                                 const float* __restrict__ x,
                                                 __half* __restrict__ Xs) {
    __shared__ int ocnt[SPAN];
    __shared__ int sc[512];
    __shared__ int cur[SPAN];
    __shared__ int sbase;
    int b = blockIdx.x, t = threadIdx.x;

    // bucket base: in-block exclusive scan of all 256 bucket counts
    int myc = cur256[t];
    sc[t] = myc;
    __syncthreads();
    for (int o = 1; o < BUCKETS; o <<= 1) {
        int v = (t >= o) ? sc[t - o] : 0;
        __syncthreads();
        sc[t] += v;
        __syncthreads();
    }
    if (t == b) sbase = sc[t] - myc;
    if (b == BUCKETS - 1 && t == 0) row_st[N_NODES] = N_EDGES;

    int n0 = b * SPAN;
    int span = N_NODES - n0; if (span > SPAN) span = SPAN;
    for (int i = t; i < SPAN; i += 256) ocnt[i] = 0;
    __syncthreads();

    int n = cur256[b];
    const int* p = bpairs + (size_t)b * BCAP;
    for (int i = t; i < n; i += 256) atomicAdd(&ocnt[p[i] & 511], 1);
    __syncthreads();
    sc[t]       = (t < span) ? ocnt[t] : 0;
    sc[t + 256] = (t + 256 < span) ? ocnt[t + 256] : 0;
    __syncthreads();
    for (int o = 1; o < 512; o <<= 1) {
        int a0 = (t >= o) ? sc[t - o] : 0;
        int a1 = sc[t + 256 - o];
        __syncthreads();
        sc[t] += a0;
        sc[t + 256] += a1;
        __syncthreads();
    }
    int base = sbase;
    for (int i = t; i < span; i += 256) {
        int start = sc[i] - ocnt[i];
        row_st[n0 + i] = base + start;
        cur[i] = start;
    }
    __syncthreads();
    for (int i = t; i < n; i += 256) {
        int e = p[i];
        int lp = atomicAdd(&cur[e & 511], 1);
        csr[base + lp] = e >> 9;
    }
    // fused scale_x for this bucket's nodes (uses ocnt degrees; indep of fill)
    for (int i = t; i < span * 32; i += 256) {
        int nl = i >> 5, f = i & 31;
        float v = (f < F_IN) ? x[(size_t)(n0 + nl) * F_IN + f] : 0.f;
        float di = rsqrtf((float)(ocnt[nl] + 1));
        Xs[(size_t)(n0 + nl) * 32 + f] = __float2half(di * v);
    }
}

// ---------------- layer 1 fused: gather(F_IN, half2-vectorized) + GEMM -> H fp16 ----------------
__global__ __launch_bounds__(256) void layer1(const __half* __restrict__ Xs,
                                              const int* __restrict__ row_st,
                                              const int* __restrict__ csr,
                                              const float* __restrict__ W,
                                              const float* __restrict__ bias,
                                              __half* __restrict__ H) {
    __shared__ float Wlds[F_IN * HID];   // 10 KB
    __shared__ float Alds[16 * F_IN];
    const int t = threadIdx.x;
    const int node0 = blockIdx.x * 16;

    for (int i = t; i < F_IN * HID; i += 256) Wlds[i] = W[i];

    // gather: group g (32 lanes) handles nodes node0+g*2+{0,1}.
    // Within a group: half hw (0/1) takes edges of parity hw; lane16 covers
    // feature pair (2*l16, 2*l16+1) via one half2 load (16 lanes / 64B row).
    const int g = t >> 5;
    const int l = t & 31;
    const int hw = l >> 4, l16 = l & 15;
    const __half2* X2 = (const __half2*)Xs;   // 16 half2 per row
    for (int k2 = 0; k2 < 2; ++k2) {
        int nn = node0 + g * 2 + k2;
        int r0 = row_st[nn], r1 = row_st[nn + 1];
        float2 acc = make_float2(0.f, 0.f);
        if (hw == 0) {
            float2 f = __half22float2(X2[(size_t)nn * 16 + l16]);
            acc = f;   // self term
        }
        int r = r0 + hw;
        for (; r + 2 < r1; r += 4) {
            float2 f0 = __half22float2(X2[(size_t)csr[r] * 16 + l16]);
            float2 f1 = __half22float2(X2[(size_t)csr[r + 2] * 16 + l16]);
            acc.x += f0.x + f1.x;
            acc.y += f0.y + f1.y;
        }
        if (r < r1) {
            float2 f = __half22float2(X2[(size_t)csr[r] * 16 + l16]);
            acc.x += f.x; acc.y += f.y;
        }
        acc.x += __shfl_xor(acc.x, 16);
        acc.y += __shfl_xor(acc.y, 16);
        if (hw == 0 && l16 < 10) {
            float di = rsqrtf((float)(r1 - r0 + 1));
            Alds[(g * 2 + k2) * F_IN + l16 * 2]     = di * acc.x;
            Alds[(g * 2 + k2) * F_IN + l16 * 2 + 1] = di * acc.y;
        }
    }
    __syncthreads();

    // GEMM phase
    const int h4 = (t & 31) * 4;
    float4 b4 = *(const float4*)&bias[h4];
    float4 acc0 = b4;
    float4 acc1 = b4;
#pragma unroll
    for (int kk = 0; kk < F_IN; ++kk) {
        float a0 = Alds[(g * 2) * F_IN + kk];
        float a1 = Alds[(g * 2 + 1) * F_IN + kk];
        float4 w = *(const float4*)&Wlds[kk * HID + h4];
        acc0.x = fmaf(a0, w.x, acc0.x);
        acc0.y = fmaf(a0, w.y, acc0.y);
        acc0.z = fmaf(a0, w.z, acc0.z);
        acc0.w = fmaf(a0, w.w, acc0.w);
        acc1.x = fmaf(a1, w.x, acc1.x);
        acc1.y = fmaf(a1, w.y, acc1.y);
        acc1.z = fmaf(a1, w.z, acc1.z);
        acc1.w = fmaf(a1, w.w, acc1.w);
    }
    {
        __half2 h0 = __floats2half2_rn(acc0.x, acc0.y);
        __half2 h1 = __floats2half2_rn(acc0.z, acc0.w);
        uint2 u; u.x = *(unsigned*)&h0; u.y = *(unsigned*)&h1;
        ((uint2*)H)[(node0 + g * 2) * 32 + (h4 >> 2)] = u;
    }
    {
        __half2 h0 = __floats2half2_rn(acc1.x, acc1.y);
        __half2 h1 = __floats2half2_rn(acc1.z, acc1.w);
        uint2 u; u.x = *(unsigned*)&h0; u.y = *(unsigned*)&h1;
        ((uint2*)H)[(node0 + g * 2 + 1) * 32 + (h4 >> 2)] = u;
    }
}

// ---------------- layers-2/3 GEMM via MFMA (column-split: 64 cols/block) ----------------
__global__ __launch_bounds__(256) void gemm_mfma(const __half* __restrict__ H,
                                                 const float* __restrict__ W,
                                                 const int* __restrict__ row_st,
                                                 __half* __restrict__ T) {
    __shared__ _Float16 Whi[64 * 128];   // 16 KB
    __shared__ _Float16 Wlo[64 * 128];   // 16 KB
    const int t = threadIdx.x;
    const int c0 = (blockIdx.x & 1) * 64;

    for (int i = t; i < 128 * 64; i += 256) {
        int k = i >> 6, c = i & 63;
        float w = W[k * HID + c0 + c];
        _Float16 hi = (_Float16)w;
        _Float16 lo = (_Float16)((w - (float)hi) * 2048.0f);
        int addr = c * 128 + (((k >> 3) ^ (c & 15)) << 3) + (k & 7);
        Whi[addr] = hi;
        Wlo[addr] = lo;
    }
    __syncthreads();

    const int wv = t >> 6;
    const int l  = t & 63;
    const int lr = l & 15;
    const int lq = l >> 4;

    for (int rep = 0; rep < 4; ++rep) {
        int strip = ((blockIdx.x >> 1) * 4 + wv) * 4 + rep;
        if (strip >= N_NODES / 16) continue;
        int n0 = strip * 16;

        f32x4_t acc[4], acl[4];
#pragma unroll
        for (int ct = 0; ct < 4; ++ct) { acc[ct] = (f32x4_t){0,0,0,0}; acl[ct] = (f32x4_t){0,0,0,0}; }

#pragma unroll
        for (int kc = 0; kc < 4; ++kc) {
            half8_t a = *(const half8_t*)(H + (size_t)(n0 + lr) * 128 + kc * 32 + lq * 8);
#pragma unroll
            for (int j = 0; j < 8; ++j) a[j] = a[j] > (_Float16)0 ? a[j] : (_Float16)0;
            int g = kc * 4 + lq;
#pragma unroll
            for (int ct = 0; ct < 4; ++ct) {
                int c = ct * 16 + lr;
                int addr = c * 128 + ((g ^ lr) << 3);
                half8_t bh = *(const half8_t*)&Whi[addr];
                half8_t bl = *(const half8_t*)&Wlo[addr];
                acc[ct] = __builtin_amdgcn_mfma_f32_16x16x32_f16(a, bh, acc[ct], 0, 0, 0);
                acl[ct] = __builtin_amdgcn_mfma_f32_16x16x32_f16(a, bl, acl[ct], 0, 0, 0);
            }
        }

        int r0 = n0 + lq * 4;
#pragma unroll
        for (int r = 0; r < 4; ++r) {
            int row = r0 + r;
            float d = rsqrtf((float)(row_st[row + 1] - row_st[row] + 1));
#pragma unroll
            for (int ct = 0; ct < 4; ++ct) {
                float v = (acc[ct][r] + acl[ct][r] * 4.8828125e-4f) * d;
                T[(size_t)row * 128 + c0 + ct * 16 + lr] = __float2half(v);
            }
        }
    }
}

// ---------------- gather (fp16 rows, unroll 8) ----------------
__global__ __launch_bounds__(256) void gather_range(const __half* __restrict__ A,
                                                    const int* __restrict__ row_st,
                                                    const int* __restrict__ csr,
                                                    const float* __restrict__ bias,
                                                    __half* __restrict__ B) {
    int t = threadIdx.x;
    int n = blockIdx.x * 8 + (t >> 5);
    int l = t & 31;
    int r0 = row_st[n], r1 = row_st[n + 1];
    float di = rsqrtf((float)(r1 - r0 + 1));
    const uint2* Af = (const uint2*)A;
    float4 acc = h4_to_f4(Af[n * 32 + l]);   // self term
    int r = r0;
    for (; r + 7 < r1; r += 8) {
        int s0 = csr[r],     s1 = csr[r + 1], s2 = csr[r + 2], s3 = csr[r + 3];
        int s4 = csr[r + 4], s5 = csr[r + 5], s6 = csr[r + 6], s7 = csr[r + 7];
        float4 v0 = h4_to_f4(Af[s0 * 32 + l]);
        float4 v1 = h4_to_f4(Af[s1 * 32 + l]);
        float4 v2 = h4_to_f4(Af[s2 * 32 + l]);
        float4 v3 = h4_to_f4(Af[s3 * 32 + l]);
        float4 v4 = h4_to_f4(Af[s4 * 32 + l]);
        float4 v5 = h4_to_f4(Af[s5 * 32 + l]);
        float4 v6 = h4_to_f4(Af[s6 * 32 + l]);
        float4 v7 = h4_to_f4(Af[s7 * 32 + l]);
        acc.x += ((v0.x + v1.x) + (v2.x + v3.x)) + ((v4.x + v5.x) + (v6.x + v7.x));
        acc.y += ((v0.y + v1.y) + (v2.y + v3.y)) + ((v4.y + v5.y) + (v6.y + v7.y));
        acc.z += ((v0.z + v1.z) + (v2.z + v3.z)) + ((v4.z + v5.z) + (v6.z + v7.z));
        acc.w += ((v0.w + v1.w) + (v2.w + v3.w)) + ((v4.w + v5.w) + (v6.w + v7.w));
    }
    for (; r + 3 < r1; r += 4) {
        int s0 = csr[r], s1 = csr[r + 1], s2 = csr[r + 2], s3 = csr[r + 3];
        float4 v0 = h4_to_f4(Af[s0 * 32 + l]);
        float4 v1 = h4_to_f4(Af[s1 * 32 + l]);
        float4 v2 = h4_to_f4(Af[s2 * 32 + l]);
        float4 v3 = h4_to_f4(Af[s3 * 32 + l]);
        acc.x += (v0.x + v1.x) + (v2.x + v3.x);
        acc.y += (v0.y + v1.y) + (v2.y + v3.y);
        acc.z += (v0.z + v1.z) + (v2.z + v3.z);
        acc.w += (v0.w + v1.w) + (v2.w + v3.w);
    }
    for (; r < r1; ++r) {
        float4 v = h4_to_f4(Af[csr[r] * 32 + l]);
        acc.x += v.x; acc.y += v.y; acc.z += v.z; acc.w += v.w;
    }
    float4 b4 = ((const float4*)bias)[l];
    __half2 h0 = __floats2half2_rn(fmaf(di, acc.x, b4.x), fmaf(di, acc.y, b4.y));
    __half2 h1 = __floats2half2_rn(fmaf(di, acc.z, b4.z), fmaf(di, acc.w, b4.w));
    uint2 u; u.x = *(unsigned*)&h0; u.y = *(unsigned*)&h1;
    ((uint2*)B)[n * 32 + l] = u;
}

// ---------------- pooling (fp16 input, fused counting; batch sorted) ----------------
__global__ __launch_bounds__(256) void pool(const __half* __restrict__ B,
                                            const int* __restrict__ batch,
                                            float* sums, float* counts) {
    int t = threadIdx.x;
    int grp = blockIdx.x * 8 + (t >> 5);
    int l = t & 31;
    int h4 = l * 4;
    int n0 = grp * 8;
    if (n0 >= N_NODES) return;
    const uint2* Bf = (const uint2*)B;
    int cur = batch[n0];
    int runlen = 0;
    float4 acc = make_float4(0.f, 0.f, 0.f, 0.f);
    for (int k = 0; k < 8; ++k) {
        int n = n0 + k;
        if (n >= N_NODES) break;
        int g = batch[n];
        if (g != cur) {
            float* sp = &sums[cur * HID + h4];
            atomicAdd(sp + 0, acc.x); atomicAdd(sp + 1, acc.y);
            atomicAdd(sp + 2, acc.z); atomicAdd(sp + 3, acc.w);
            if (l == 0) atomicAdd(&counts[cur], (float)runlen);
            acc = make_float4(0.f, 0.f, 0.f, 0.f);
            runlen = 0;
            cur = g;
        }
        float4 v = h4_to_f4(Bf[n * 32 + l]);
        acc.x += fmaxf(v.x, 0.f);
        acc.y += fmaxf(v.y, 0.f);
        acc.z += fmaxf(v.z, 0.f);
        acc.w += fmaxf(v.w, 0.f);
        ++runlen;
    }
    float* sp = &sums[cur * HID + h4];
    atomicAdd(sp + 0, acc.x); atomicAdd(sp + 1, acc.y);
    atomicAdd(sp + 2, acc.z); atomicAdd(sp + 3, acc.w);
    if (l == 0) atomicAdd(&counts[cur], (float)runlen);
}

__global__ void final_gemm(const float* __restrict__ sums, const float* __restrict__ counts,
                           const float* __restrict__ Wout, const float* __restrict__ bout,
                           float* __restrict__ out) {
    int g = blockIdx.x;
    int o = threadIdx.x;   // 64
    __shared__ float p[HID];
    for (int k = o; k < HID; k += 64) p[k] = sums[g * HID + k];
    __syncthreads();
    float inv = 1.0f / fmaxf(counts[g], 1.0f);
    float acc = 0.f;
#pragma unroll 8
    for (int k = 0; k < HID; ++k)
        acc = fmaf(p[k], Wout[k * OUT_F + o], acc);
    out[g * OUT_F + o] = fmaf(inv, acc, bout[o]);
}

extern "C" void kernel_launch(void* const* d_in, const int* in_sizes, int n_in,
                              void* d_out, int out_size, void* d_ws, size_t ws_size,
                              hipStream_t stream) {
    const float* x     = (const float*)d_in[0];
    const int*   ei    = (const int*)d_in[1];
    const int*   batch = (const int*)d_in[2];
    const float* W1    = (const float*)d_in[3];
    const float* b1    = (const float*)d_in[4];
    const float* W2    = (const float*)d_in[5];
    const float* b2    = (const float*)d_in[6];
    const float* W3    = (const float*)d_in[7];
    const float* b3    = (const float*)d_in[8];
    const float* Wout  = (const float*)d_in[9];
    const float* bout  = (const float*)d_in[10];
    float* out = (float*)d_out;

    const int* src = ei;
    const int* dst = ei + N_EDGES;

    // workspace (within proven footprint)
    float* A      = (float*)d_ws;                        // 12.8M floats
    float* Breg   = A + (size_t)N_NODES * HID;           // 12.8M floats
    int*   row_st = (int*)(Breg + (size_t)N_NODES * HID);// 100001 ints
    float* sums   = (float*)(row_st + N_NODES + 1);      // 65536
    float* counts = sums + N_GRAPHS * HID;               // 512
    int*   cur256 = (int*)(counts + N_GRAPHS);           // 256 (contiguous w/ sums+counts)
    int*   csr    = cur256 + BUCKETS;                    // 1.6M ints

    int*    bpairs = (int*)A;                              // 7.17 MB overlay
    __half* Xs     = (__half*)((char*)A + 7168000);        // 6.4 MB, after bpairs
    __half* T      = (__half*)A;                           // 25.6 MB msg table (after layer1)
    __half* H      = (__half*)Breg;                        // 25.6 MB activation table

    // 1. single contiguous zero (sums+counts+cur256) + CSR build (fused scan+scale_x)
    hipMemsetAsync(sums, 0, (size_t)(N_GRAPHS * HID + N_GRAPHS + BUCKETS) * 4, stream);
    partition<<<(N_EDGES + EPB - 1) / EPB, 256, 0, stream>>>(src, dst, bpairs, cur256);
    csr_build<<<BUCKETS, 256, 0, stream>>>(bpairs, cur256, row_st, csr, x, Xs);

    // 2. layer 1: fused gather(F_IN)+GEMM
    layer1<<<N_NODES / 16, 256, 0, stream>>>(Xs, row_st, csr, W1, b1, H);

    // 3. layers 2/3: MFMA transform (ReLU fused) then aggregate
    gemm_mfma<<<782, 256, 0, stream>>>(H, W2, row_st, T);
    gather_range<<<N_NODES / 8, 256, 0, stream>>>(T, row_st, csr, b2, H);
    gemm_mfma<<<782, 256, 0, stream>>>(H, W3, row_st, T);
    gather_range<<<N_NODES / 8, 256, 0, stream>>>(T, row_st, csr, b3, H);

    // 4. pool + head
    pool<<<(N_NODES / 8 + 7) / 8, 256, 0, stream>>>(H, batch, sums, counts);
    final_gemm<<<N_GRAPHS, 64, 0, stream>>>(sums, counts, Wout, bout, out);
}

// Round 10
// 373.480 us; speedup vs baseline: 1.1023x; 1.0847x over previous
//
#include <hip/hip_runtime.h>
#include <hip/hip_fp16.h>

#define N_NODES 100000
#define N_EDGES 1600000
#define N_GRAPHS 512
#define F_IN 20
#define HID 128
#define OUT_F 64

#define BUCKETS 256
#define SPAN 391        // ceil(N_NODES / BUCKETS)
#define BCAP 7000       // per-bucket capacity (mean 6250, ~9 sigma headroom)
#define EPB 4096        // edges per partition block (512 threads x 8)

typedef _Float16 half8_t __attribute__((ext_vector_type(8)));
typedef float f32x4_t __attribute__((ext_vector_type(4)));

__device__ inline float4 h4_to_f4(uint2 u) {
    __half2 h0 = *(__half2*)&u.x;
    __half2 h1 = *(__half2*)&u.y;
    float2 f0 = __half22float2(h0);
    float2 f1 = __half22float2(h1);
    return make_float4(f0.x, f0.y, f1.x, f1.y);
}

// ---------------- partition edges into 256 dst-range buckets (512 thr) ----------------
__global__ __launch_bounds__(512) void partition(const int* __restrict__ src,
                                                 const int* __restrict__ dst,
                                                 int* __restrict__ bpairs,
                                                 int* cur256) {
    __shared__ int lcnt[8][BUCKETS];   // 8 KB
    __shared__ int woff[8][BUCKETS];   // 8 KB
    int t = threadIdx.x;
    int wv = t >> 6;
    for (int i = t; i < 8 * BUCKETS; i += 512) ((int*)lcnt)[i] = 0;
    __syncthreads();
    int base = blockIdx.x * EPB;
    int myb[8], myp[8], myr[8];
#pragma unroll
    for (int i = 0; i < 8; ++i) {
        int e = base + i * 512 + t;
        int b = -1, p = 0, rk = 0;
        if (e < N_EDGES) {
            int s = src[e], d = dst[e];
            b = d / SPAN;
            p = (s << 9) | (d - b * SPAN);
            rk = atomicAdd(&lcnt[wv][b], 1);
        }
        myb[i] = b; myp[i] = p; myr[i] = rk;
    }
    __syncthreads();
    if (t < BUCKETS) {
        int c[8], tot = 0;
#pragma unroll
        for (int w = 0; w < 8; ++w) { c[w] = lcnt[w][t]; tot += c[w]; }
        int gb = atomicAdd(&cur256[t], tot);
#pragma unroll
        for (int w = 0; w < 8; ++w) { woff[w][t] = gb; gb += c[w]; }
    }
    __syncthreads();
#pragma unroll
    for (int i = 0; i < 8; ++i) {
        int b = myb[i];
        if (b >= 0) {
            int p = woff[wv][b] + myr[i];
            if (p < BCAP) bpairs[(size_t)b * BCAP + p] = myp[i];
        }
    }
}

// ---------------- per-bucket CSR build, 512 thr (fused bbase scan + scale_x) ----------------
__global__ __launch_bounds__(512) void csr_build(const int* __restrict__ bpairs,
                                                 const int* __restrict__ cur256,
                                                 int* __restrict__ row_st,
                                                 int* __restrict__ csr,
                                                 const float* __restrict__ x,
                                                 __half* __restrict__ Xs) {
    __shared__ int ocnt[SPAN];
    __shared__ int sc[512];
    __shared__ int cur[SPAN];
    __shared__ int sbase;
    int b = blockIdx.x, t = threadIdx.x;

    // bucket base: exclusive scan of 256 bucket counts (first 256 threads)
    int myc = (t < BUCKETS) ? cur256[t] : 0;
    sc[t] = myc;
    __syncthreads();
    for (int o = 1; o < BUCKETS; o <<= 1) {
        int v = (t >= o) ? sc[t - o] : 0;
        __syncthreads();
        sc[t] += v;
        __syncthreads();
    }
    if (t == b) sbase = sc[t] - myc;
    if (b == BUCKETS - 1 && t == 0) row_st[N_NODES] = N_EDGES;

    int n0 = b * SPAN;
    int span = N_NODES - n0; if (span > SPAN) span = SPAN;
    if (t < SPAN) ocnt[t] = 0;
    __syncthreads();

    int n = cur256[b];
    const int* p = bpairs + (size_t)b * BCAP;
    for (int i = t; i < n; i += 512) atomicAdd(&ocnt[p[i] & 511], 1);
    __syncthreads();
    sc[t] = (t < span) ? ocnt[t] : 0;
    __syncthreads();
    for (int o = 1; o < 512; o <<= 1) {
        int v = (t >= o) ? sc[t - o] : 0;
        __syncthreads();
        sc[t] += v;
        __syncthreads();
    }
    int base = sbase;
    if (t < span) {
        int start = sc[t] - ocnt[t];
        row_st[n0 + t] = base + start;
        cur[t] = start;
    }
    __syncthreads();
    for (int i = t; i < n; i += 512) {
        int e = p[i];
        int lp = atomicAdd(&cur[e & 511], 1);
        csr[base + lp] = e >> 9;
    }
    // fused scale_x for this bucket's nodes
    for (int i = t; i < span * 32; i += 512) {
        int nl = i >> 5, f = i & 31;
        float v = (f < F_IN) ? x[(size_t)(n0 + nl) * F_IN + f] : 0.f;
        float di = rsqrtf((float)(ocnt[nl] + 1));
        Xs[(size_t)(n0 + nl) * 32 + f] = __float2half(di * v);
    }
}

// ---------------- layer 1 fused: gather(F_IN) + GEMM -> H fp16 ----------------
// Each 16-lane half owns one node: lane covers a feature pair via one half2
// (16 x 4B = full 64B row per edge). No cross-lane reduction needed.
__global__ __launch_bounds__(256) void layer1(const __half* __restrict__ Xs,
                                              const int* __restrict__ row_st,
                                              const int* __restrict__ csr,
                                              const float* __restrict__ W,
                                              const float* __restrict__ bias,
                                              __half* __restrict__ H) {
    __shared__ float Wlds[F_IN * HID];   // 10 KB
    __shared__ float Alds[16 * F_IN];
    const int t = threadIdx.x;
    const int node0 = blockIdx.x * 16;

    for (int i = t; i < F_IN * HID; i += 256) Wlds[i] = W[i];

    const int h16 = t >> 4;          // 0..15 -> local node
    const int l16 = t & 15;          // feature pair
    const __half2* X2 = (const __half2*)Xs;   // 16 half2 per row
    {
        int nn = node0 + h16;
        int r0 = row_st[nn], r1 = row_st[nn + 1];
        float2 f = __half22float2(X2[(size_t)nn * 16 + l16]);
        float2 acc = f;   // self term
        int r = r0;
        for (; r + 1 < r1; r += 2) {
            float2 f0 = __half22float2(X2[(size_t)csr[r] * 16 + l16]);
            float2 f1 = __half22float2(X2[(size_t)csr[r + 1] * 16 + l16]);
            acc.x += f0.x + f1.x;
            acc.y += f0.y + f1.y;
        }
        if (r < r1) {
            float2 f2 = __half22float2(X2[(size_t)csr[r] * 16 + l16]);
            acc.x += f2.x; acc.y += f2.y;
        }
        if (l16 < 10) {
            float di = rsqrtf((float)(r1 - r0 + 1));
            Alds[h16 * F_IN + l16 * 2]     = di * acc.x;
            Alds[h16 * F_IN + l16 * 2 + 1] = di * acc.y;
        }
    }
    __syncthreads();

    // GEMM phase
    const int g  = t >> 5;
    const int h4 = (t & 31) * 4;
    float4 b4 = *(const float4*)&bias[h4];
    float4 acc0 = b4;
    float4 acc1 = b4;
#pragma unroll
    for (int kk = 0; kk < F_IN; ++kk) {
        float a0 = Alds[(g * 2) * F_IN + kk];
        float a1 = Alds[(g * 2 + 1) * F_IN + kk];
        float4 w = *(const float4*)&Wlds[kk * HID + h4];
        acc0.x = fmaf(a0, w.x, acc0.x);
        acc0.y = fmaf(a0, w.y, acc0.y);
        acc0.z = fmaf(a0, w.z, acc0.z);
        acc0.w = fmaf(a0, w.w, acc0.w);
        acc1.x = fmaf(a1, w.x, acc1.x);
        acc1.y = fmaf(a1, w.y, acc1.y);
        acc1.z = fmaf(a1, w.z, acc1.z);
        acc1.w = fmaf(a1, w.w, acc1.w);
    }
    {
        __half2 h0 = __floats2half2_rn(acc0.x, acc0.y);
        __half2 h1 = __floats2half2_rn(acc0.z, acc0.w);
        uint2 u; u.x = *(unsigned*)&h0; u.y = *(unsigned*)&h1;
        ((uint2*)H)[(node0 + g * 2) * 32 + (h4 >> 2)] = u;
    }
    {
        __half2 h0 = __floats2half2_rn(acc1.x, acc1.y);
        __half2 h1 = __floats2half2_rn(acc1.z, acc1.w);
        uint2 u; u.x = *(unsigned*)&h0; u.y = *(unsigned*)&h1;
        ((uint2*)H)[(node0 + g * 2 + 1) * 32 + (h4 >> 2)] = u;
    }
}

// ---------------- layers-2/3 GEMM via MFMA (column-split: 64 cols/block) ----------------
__global__ __launch_bounds__(256) void gemm_mfma(const __half* __restrict__ H,
                                                 const float* __restrict__ W,
                                                 const int* __restrict__ row_st,
                                                 __half* __restrict__ T) {
    __shared__ _Float16 Whi[64 * 128];   // 16 KB
    __shared__ _Float16 Wlo[64 * 128];   // 16 KB
    const int t = threadIdx.x;
    const int c0 = (blockIdx.x & 1) * 64;

    for (int i = t; i < 128 * 64; i += 256) {
        int k = i >> 6, c = i & 63;
        float w = W[k * HID + c0 + c];
        _Float16 hi = (_Float16)w;
        _Float16 lo = (_Float16)((w - (float)hi) * 2048.0f);
        int addr = c * 128 + (((k >> 3) ^ (c & 15)) << 3) + (k & 7);
        Whi[addr] = hi;
        Wlo[addr] = lo;
    }
    __syncthreads();

    const int wv = t >> 6;
    const int l  = t & 63;
    const int lr = l & 15;
    const int lq = l >> 4;

    for (int rep = 0; rep < 4; ++rep) {
        int strip = ((blockIdx.x >> 1) * 4 + wv) * 4 + rep;
        if (strip >= N_NODES / 16) continue;
        int n0 = strip * 16;

        f32x4_t acc[4], acl[4];
#pragma unroll
        for (int ct = 0; ct < 4; ++ct) { acc[ct] = (f32x4_t){0,0,0,0}; acl[ct] = (f32x4_t){0,0,0,0}; }

#pragma unroll
        for (int kc = 0; kc < 4; ++kc) {
            half8_t a = *(const half8_t*)(H + (size_t)(n0 + lr) * 128 + kc * 32 + lq * 8);
#pragma unroll
            for (int j = 0; j < 8; ++j) a[j] = a[j] > (_Float16)0 ? a[j] : (_Float16)0;
            int g = kc * 4 + lq;
#pragma unroll
            for (int ct = 0; ct < 4; ++ct) {
                int c = ct * 16 + lr;
                int addr = c * 128 + ((g ^ lr) << 3);
                half8_t bh = *(const half8_t*)&Whi[addr];
                half8_t bl = *(const half8_t*)&Wlo[addr];
                acc[ct] = __builtin_amdgcn_mfma_f32_16x16x32_f16(a, bh, acc[ct], 0, 0, 0);
                acl[ct] = __builtin_amdgcn_mfma_f32_16x16x32_f16(a, bl, acl[ct], 0, 0, 0);
            }
        }

        int r0 = n0 + lq * 4;
#pragma unroll
        for (int r = 0; r < 4; ++r) {
            int row = r0 + r;
            float d = rsqrtf((float)(row_st[row + 1] - row_st[row] + 1));
#pragma unroll
            for (int ct = 0; ct < 4; ++ct) {
                float v = (acc[ct][r] + acl[ct][r] * 4.8828125e-4f) * d;
                T[(size_t)row * 128 + c0 + ct * 16 + lr] = __float2half(v);
            }
        }
    }
}

// ---------------- gather layer 2 (fp16 rows, unroll 8) ----------------
__global__ __launch_bounds__(256) void gather_range(const __half* __restrict__ A,
                                                    const int* __restrict__ row_st,
                                                    const int* __restrict__ csr,
                                                    const float* __restrict__ bias,
                                                    __half* __restrict__ B) {
    int t = threadIdx.x;
    int n = blockIdx.x * 8 + (t >> 5);
    int l = t & 31;
    int r0 = row_st[n], r1 = row_st[n + 1];
    float di = rsqrtf((float)(r1 - r0 + 1));
    const uint2* Af = (const uint2*)A;
    float4 acc = h4_to_f4(Af[n * 32 + l]);   // self term
    int r = r0;
    for (; r + 7 < r1; r += 8) {
        int s0 = csr[r],     s1 = csr[r + 1], s2 = csr[r + 2], s3 = csr[r + 3];
        int s4 = csr[r + 4], s5 = csr[r + 5], s6 = csr[r + 6], s7 = csr[r + 7];
        float4 v0 = h4_to_f4(Af[s0 * 32 + l]);
        float4 v1 = h4_to_f4(Af[s1 * 32 + l]);
        float4 v2 = h4_to_f4(Af[s2 * 32 + l]);
        float4 v3 = h4_to_f4(Af[s3 * 32 + l]);
        float4 v4 = h4_to_f4(Af[s4 * 32 + l]);
        float4 v5 = h4_to_f4(Af[s5 * 32 + l]);
        float4 v6 = h4_to_f4(Af[s6 * 32 + l]);
        float4 v7 = h4_to_f4(Af[s7 * 32 + l]);
        acc.x += ((v0.x + v1.x) + (v2.x + v3.x)) + ((v4.x + v5.x) + (v6.x + v7.x));
        acc.y += ((v0.y + v1.y) + (v2.y + v3.y)) + ((v4.y + v5.y) + (v6.y + v7.y));
        acc.z += ((v0.z + v1.z) + (v2.z + v3.z)) + ((v4.z + v5.z) + (v6.z + v7.z));
        acc.w += ((v0.w + v1.w) + (v2.w + v3.w)) + ((v4.w + v5.w) + (v6.w + v7.w));
    }
    for (; r + 3 < r1; r += 4) {
        int s0 = csr[r], s1 = csr[r + 1], s2 = csr[r + 2], s3 = csr[r + 3];
        float4 v0 = h4_to_f4(Af[s0 * 32 + l]);
        float4 v1 = h4_to_f4(Af[s1 * 32 + l]);
        float4 v2 = h4_to_f4(Af[s2 * 32 + l]);
        float4 v3 = h4_to_f4(Af[s3 * 32 + l]);
        acc.x += (v0.x + v1.x) + (v2.x + v3.x);
        acc.y += (v0.y + v1.y) + (v2.y + v3.y);
        acc.z += (v0.z + v1.z) + (v2.z + v3.z);
        acc.w += (v0.w + v1.w) + (v2.w + v3.w);
    }
    for (; r < r1; ++r) {
        float4 v = h4_to_f4(Af[csr[r] * 32 + l]);
        acc.x += v.x; acc.y += v.y; acc.z += v.z; acc.w += v.w;
    }
    float4 b4 = ((const float4*)bias)[l];
    __half2 h0 = __floats2half2_rn(fmaf(di, acc.x, b4.x), fmaf(di, acc.y, b4.y));
    __half2 h1 = __floats2half2_rn(fmaf(di, acc.z, b4.z), fmaf(di, acc.w, b4.w));
    uint2 u; u.x = *(unsigned*)&h0; u.y = *(unsigned*)&h1;
    ((uint2*)B)[n * 32 + l] = u;
}

// ---------------- layer-3 gather fused with ReLU + mean-pool accumulation ----------------
// Each 32-lane group gathers 8 consecutive nodes, run-accumulates (batch is
// sorted), flushes one atomic set per graph-run. No H write, no pool pass.
__global__ __launch_bounds__(256) void gather_pool(const __half* __restrict__ A,
                                                   const int* __restrict__ row_st,
                                                   const int* __restrict__ csr,
                                                   const float* __restrict__ bias,
                                                   const int* __restrict__ batch,
                                                   float* sums, float* counts) {
    int t = threadIdx.x;
    int l = t & 31;
    int n0 = (blockIdx.x * 8 + (t >> 5)) * 8;
    if (n0 >= N_NODES) return;
    const uint2* Af = (const uint2*)A;
    float4 b4 = ((const float4*)bias)[l];
    int cur = batch[n0];
    int runlen = 0;
    float4 pacc = make_float4(0.f, 0.f, 0.f, 0.f);
    for (int k = 0; k < 8; ++k) {
        int n = n0 + k;
        if (n >= N_NODES) break;
        int g = batch[n];
        if (g != cur) {
            float* sp = &sums[cur * HID + l * 4];
            atomicAdd(sp + 0, pacc.x); atomicAdd(sp + 1, pacc.y);
            atomicAdd(sp + 2, pacc.z); atomicAdd(sp + 3, pacc.w);
            if (l == 0) atomicAdd(&counts[cur], (float)runlen);
            pacc = make_float4(0.f, 0.f, 0.f, 0.f);
            runlen = 0;
            cur = g;
        }
        int r0 = row_st[n], r1 = row_st[n + 1];
        float4 acc = h4_to_f4(Af[n * 32 + l]);   // self term
        int r = r0;
        for (; r + 7 < r1; r += 8) {
            int s0 = csr[r],     s1 = csr[r + 1], s2 = csr[r + 2], s3 = csr[r + 3];
            int s4 = csr[r + 4], s5 = csr[r + 5], s6 = csr[r + 6], s7 = csr[r + 7];
            float4 v0 = h4_to_f4(Af[s0 * 32 + l]);
            float4 v1 = h4_to_f4(Af[s1 * 32 + l]);
            float4 v2 = h4_to_f4(Af[s2 * 32 + l]);
            float4 v3 = h4_to_f4(Af[s3 * 32 + l]);
            float4 v4 = h4_to_f4(Af[s4 * 32 + l]);
            float4 v5 = h4_to_f4(Af[s5 * 32 + l]);
            float4 v6 = h4_to_f4(Af[s6 * 32 + l]);
            float4 v7 = h4_to_f4(Af[s7 * 32 + l]);
            acc.x += ((v0.x + v1.x) + (v2.x + v3.x)) + ((v4.x + v5.x) + (v6.x + v7.x));
            acc.y += ((v0.y + v1.y) + (v2.y + v3.y)) + ((v4.y + v5.y) + (v6.y + v7.y));
            acc.z += ((v0.z + v1.z) + (v2.z + v3.z)) + ((v4.z + v5.z) + (v6.z + v7.z));
            acc.w += ((v0.w + v1.w) + (v2.w + v3.w)) + ((v4.w + v5.w) + (v6.w + v7.w));
        }
        for (; r + 3 < r1; r += 4) {
            int s0 = csr[r], s1 = csr[r + 1], s2 = csr[r + 2], s3 = csr[r + 3];
            float4 v0 = h4_to_f4(Af[s0 * 32 + l]);
            float4 v1 = h4_to_f4(Af[s1 * 32 + l]);
            float4 v2 = h4_to_f4(Af[s2 * 32 + l]);
            float4 v3 = h4_to_f4(Af[s3 * 32 + l]);
            acc.x += (v0.x + v1.x) + (v2.x + v3.x);
            acc.y += (v0.y + v1.y) + (v2.y + v3.y);
            acc.z += (v0.z + v1.z) + (v2.z + v3.z);
            acc.w += (v0.w + v1.w) + (v2.w + v3.w);
        }
        for (; r < r1; ++r) {
            float4 v = h4_to_f4(Af[csr[r] * 32 + l]);
            acc.x += v.x; acc.y += v.y; acc.z += v.z; acc.w += v.w;
        }
        float di = rsqrtf((float)(r1 - r0 + 1));
        pacc.x += fmaxf(fmaf(di, acc.x, b4.x), 0.f);
        pacc.y += fmaxf(fmaf(di, acc.y, b4.y), 0.f);
        pacc.z += fmaxf(fmaf(di, acc.z, b4.z), 0.f);
        pacc.w += fmaxf(fmaf(di, acc.w, b4.w), 0.f);
        ++runlen;
    }
    float* sp = &sums[cur * HID + l * 4];
    atomicAdd(sp + 0, pacc.x); atomicAdd(sp + 1, pacc.y);
    atomicAdd(sp + 2, pacc.z); atomicAdd(sp + 3, pacc.w);
    if (l == 0) atomicAdd(&counts[cur], (float)runlen);
}

__global__ void final_gemm(const float* __restrict__ sums, const float* __restrict__ counts,
                           const float* __restrict__ Wout, const float* __restrict__ bout,
                           float* __restrict__ out) {
    int g = blockIdx.x;
    int o = threadIdx.x;   // 64
    __shared__ float p[HID];
    for (int k = o; k < HID; k += 64) p[k] = sums[g * HID + k];
    __syncthreads();
    float inv = 1.0f / fmaxf(counts[g], 1.0f);
    float acc = 0.f;
#pragma unroll 8
    for (int k = 0; k < HID; ++k)
        acc = fmaf(p[k], Wout[k * OUT_F + o], acc);
    out[g * OUT_F + o] = fmaf(inv, acc, bout[o]);
}

extern "C" void kernel_launch(void* const* d_in, const int* in_sizes, int n_in,
                              void* d_out, int out_size, void* d_ws, size_t ws_size,
                              hipStream_t stream) {
    const float* x     = (const float*)d_in[0];
    const int*   ei    = (const int*)d_in[1];
    const int*   batch = (const int*)d_in[2];
    const float* W1    = (const float*)d_in[3];
    const float* b1    = (const float*)d_in[4];
    const float* W2    = (const float*)d_in[5];
    const float* b2    = (const float*)d_in[6];
    const float* W3    = (const float*)d_in[7];
    const float* b3    = (const float*)d_in[8];
    const float* Wout  = (const float*)d_in[9];
    const float* bout  = (const float*)d_in[10];
    float* out = (float*)d_out;

    const int* src = ei;
    const int* dst = ei + N_EDGES;

    // workspace (within proven footprint)
    float* A      = (float*)d_ws;                        // 12.8M floats
    float* Breg   = A + (size_t)N_NODES * HID;           // 12.8M floats
    int*   row_st = (int*)(Breg + (size_t)N_NODES * HID);// 100001 ints
    float* sums   = (float*)(row_st + N_NODES + 1);      // 65536
    float* counts = sums + N_GRAPHS * HID;               // 512
    int*   cur256 = (int*)(counts + N_GRAPHS);           // 256 (contiguous w/ sums+counts)
    int*   csr    = cur256 + BUCKETS;                    // 1.6M ints

    int*    bpairs = (int*)A;                              // 7.17 MB overlay
    __half* Xs     = (__half*)((char*)A + 7168000);        // 6.4 MB, after bpairs
    __half* T      = (__half*)A;                           // 25.6 MB msg table (after layer1)
    __half* H      = (__half*)Breg;                        // 25.6 MB activation table

    // 1. single contiguous zero (sums+counts+cur256) + CSR build
    hipMemsetAsync(sums, 0, (size_t)(N_GRAPHS * HID + N_GRAPHS + BUCKETS) * 4, stream);
    partition<<<(N_EDGES + EPB - 1) / EPB, 512, 0, stream>>>(src, dst, bpairs, cur256);
    csr_build<<<BUCKETS, 512, 0, stream>>>(bpairs, cur256, row_st, csr, x, Xs);

    // 2. layer 1: fused gather(F_IN)+GEMM
    layer1<<<N_NODES / 16, 256, 0, stream>>>(Xs, row_st, csr, W1, b1, H);

    // 3. layers 2/3
    gemm_mfma<<<782, 256, 0, stream>>>(H, W2, row_st, T);
    gather_range<<<N_NODES / 8, 256, 0, stream>>>(T, row_st, csr, b2, H);
    gemm_mfma<<<782, 256, 0, stream>>>(H, W3, row_st, T);
    gather_pool<<<(N_NODES + 63) / 64, 256, 0, stream>>>(T, row_st, csr, b3, batch, sums, counts);

    // 4. head
    final_gemm<<<N_GRAPHS, 64, 0, stream>>>(sums, counts, Wout, bout, out);
}